// Round 1
// baseline (1863.396 us; speedup 1.0000x reference)
//
#include <hip/hip_runtime.h>
#include <hip/hip_bf16.h>
#include <math.h>

#define N_PTS 8192
#define D_FEAT 64
#define TPB 256

__global__ __launch_bounds__(TPB) void mean_nn_dist_kernel(
    const float* __restrict__ x, float* __restrict__ mean_dists) {
    __shared__ __align__(16) float s_xi[D_FEAT];
    __shared__ float s_d[N_PTS];          // 32 KB: all distances for row i
    __shared__ float s_rv[TPB];
    __shared__ int   s_ri[TPB];

    const int i = blockIdx.x;
    const int t = threadIdx.x;
    const float INF = __builtin_inff();

    if (t < D_FEAT) s_xi[t] = x[i * D_FEAT + t];
    __syncthreads();

    // x2_i (redundant per thread; reads are LDS broadcasts)
    float x2i = 0.f;
    #pragma unroll
    for (int d = 0; d < D_FEAT; ++d) { float v = s_xi[d]; x2i += v * v; }

    // distances for all j
    const float4* s_xi4 = reinterpret_cast<const float4*>(s_xi);
    for (int j = t; j < N_PTS; j += TPB) {
        const float4* xj = reinterpret_cast<const float4*>(x + j * D_FEAT);
        float dot = 0.f, x2j = 0.f;
        #pragma unroll
        for (int q = 0; q < D_FEAT / 4; ++q) {
            float4 v = xj[q];
            float4 w = s_xi4[q];
            dot += v.x * w.x + v.y * w.y + v.z * w.z + v.w * w.w;
            x2j += v.x * v.x + v.y * v.y + v.z * v.z + v.w * v.w;
        }
        float d2 = x2i + x2j - 2.f * dot;
        float dist = (d2 > 0.f) ? sqrtf(d2) : 0.f;
        s_d[j] = (j == i) ? INF : dist;   // exclude self
    }
    __syncthreads();

    // 16 iterated block-argmin extractions
    float sum = 0.f;
    for (int it = 0; it < 16; ++it) {
        float lv = INF; int li = -1;
        for (int j = t; j < N_PTS; j += TPB) {
            float v = s_d[j];
            if (v < lv) { lv = v; li = j; }
        }
        s_rv[t] = lv; s_ri[t] = li;
        __syncthreads();
        for (int off = TPB / 2; off > 0; off >>= 1) {
            if (t < off) {
                if (s_rv[t + off] < s_rv[t]) {
                    s_rv[t] = s_rv[t + off];
                    s_ri[t] = s_ri[t + off];
                }
            }
            __syncthreads();
        }
        if (t == 0) {
            sum += s_rv[0];
            s_d[s_ri[0]] = INF;          // remove extracted min
        }
        __syncthreads();
    }

    if (t == 0) mean_dists[i] = sum * (1.f / 16.f);
}

__global__ __launch_bounds__(1024) void loss_kernel(
    const float* __restrict__ md, float* __restrict__ out) {
    __shared__ float s[1024];
    const int t = threadIdx.x;

    // pass 1: max
    float m = -__builtin_inff();
    for (int j = t; j < N_PTS; j += 1024) m = fmaxf(m, md[j]);
    s[t] = m; __syncthreads();
    for (int off = 512; off > 0; off >>= 1) {
        if (t < off) s[t] = fmaxf(s[t], s[t + off]);
        __syncthreads();
    }
    m = s[0]; __syncthreads();

    // pass 2: sum(exp(v-m)) and sum(v)
    float se = 0.f, sm = 0.f;
    for (int j = t; j < N_PTS; j += 1024) {
        float v = md[j];
        se += expf(v - m);
        sm += v;
    }
    s[t] = se; __syncthreads();
    for (int off = 512; off > 0; off >>= 1) {
        if (t < off) s[t] += s[t + off];
        __syncthreads();
    }
    float S = s[0]; __syncthreads();
    s[t] = sm; __syncthreads();
    for (int off = 512; off > 0; off >>= 1) {
        if (t < off) s[t] += s[t + off];
        __syncthreads();
    }
    float M = s[0];

    if (t == 0) {
        const float n = (float)N_PTS;
        float lse = m + logf(S);
        // loss = -log(n) - mean(md) + logsumexp(md)
        out[0] = -logf(n) - M / n + lse;
    }
}

extern "C" void kernel_launch(void* const* d_in, const int* in_sizes, int n_in,
                              void* d_out, int out_size, void* d_ws, size_t ws_size,
                              hipStream_t stream) {
    const float* x = (const float*)d_in[0];
    float* out = (float*)d_out;
    float* mean_dists = (float*)d_ws;   // 8192 floats = 32 KB scratch

    mean_nn_dist_kernel<<<N_PTS, TPB, 0, stream>>>(x, mean_dists);
    loss_kernel<<<1, 1024, 0, stream>>>(mean_dists, out);
}

// Round 2
// 266.814 us; speedup vs baseline: 6.9839x; 6.9839x over previous
//
#include <hip/hip_runtime.h>
#include <hip/hip_bf16.h>
#include <math.h>

#define N_PTS 8192
#define D_FEAT 64
#define TPB 512            // 8 waves
#define TM 32              // rows per block
#define R_PW 4             // rows per wave
#define TJ 256             // j-tile size
#define NTILE (N_PTS / TJ) // 32
#define DH 32              // d-dimension half (stage 32 dims at a time)

__global__ __launch_bounds__(256) void norms_kernel(
    const float* __restrict__ x, float* __restrict__ x2) {
    int i = blockIdx.x * 256 + threadIdx.x;
    const float4* xr = reinterpret_cast<const float4*>(x + (size_t)i * D_FEAT);
    float s = 0.f;
    #pragma unroll
    for (int q = 0; q < D_FEAT / 4; ++q) {
        float4 v = xr[q];
        s += v.x * v.x + v.y * v.y + v.z * v.z + v.w * v.w;
    }
    x2[i] = s;
}

__global__ __launch_bounds__(TPB, 2) void nn16_kernel(
    const float* __restrict__ x, const float* __restrict__ x2,
    float* __restrict__ md) {
    __shared__ __align__(16) float s_xT[DH][TJ];      // 32 KB transposed tile
    __shared__ __align__(16) float s_xi[TM][D_FEAT];  // 8 KB own rows
    __shared__ float s_x2t[TJ];                       // 1 KB

    const int t = threadIdx.x;
    const int lane = t & 63;
    const int w = t >> 6;            // wave 0..7
    const int row0 = blockIdx.x * TM;
    const int my_r0 = w * R_PW;      // local row base for this wave
    const float INF = __builtin_inff();

    // stage this block's 32 rows (2048 floats, 1 float4/thread, coalesced)
    {
        const float4* src = reinterpret_cast<const float4*>(x + (size_t)row0 * D_FEAT);
        reinterpret_cast<float4*>(&s_xi[0][0])[t] = src[t];
    }

    float x2i[R_PW];
    #pragma unroll
    for (int r = 0; r < R_PW; ++r) x2i[r] = x2[row0 + my_r0 + r];

    // per-row sorted (ascending) top-16 of squared distances, register-resident
    float t16[R_PW][16];
    #pragma unroll
    for (int r = 0; r < R_PW; ++r)
        #pragma unroll
        for (int k = 0; k < 16; ++k) t16[r][k] = INF;

    for (int tile = 0; tile < NTILE; ++tile) {
        const int j0 = tile * TJ;
        float acc[R_PW][4];
        #pragma unroll
        for (int r = 0; r < R_PW; ++r)
            #pragma unroll
            for (int jj = 0; jj < 4; ++jj) acc[r][jj] = 0.f;

        #pragma unroll
        for (int half = 0; half < 2; ++half) {
            __syncthreads();   // previous consume done (and xi-stage on first pass)
            // stage 256 rows x 32 dims, transposed. thread: row jr, 16-float segment
            {
                const int jr = t >> 1;
                const int seg = (t & 1) * 16;
                const float* srcp = x + (size_t)(j0 + jr) * D_FEAT + half * DH + seg;
                const float4* s4 = reinterpret_cast<const float4*>(srcp);
                float4 a = s4[0], b = s4[1], c = s4[2], d = s4[3];
                s_xT[seg +  0][jr] = a.x; s_xT[seg +  1][jr] = a.y;
                s_xT[seg +  2][jr] = a.z; s_xT[seg +  3][jr] = a.w;
                s_xT[seg +  4][jr] = b.x; s_xT[seg +  5][jr] = b.y;
                s_xT[seg +  6][jr] = b.z; s_xT[seg +  7][jr] = b.w;
                s_xT[seg +  8][jr] = c.x; s_xT[seg +  9][jr] = c.y;
                s_xT[seg + 10][jr] = c.z; s_xT[seg + 11][jr] = c.w;
                s_xT[seg + 12][jr] = d.x; s_xT[seg + 13][jr] = d.y;
                s_xT[seg + 14][jr] = d.z; s_xT[seg + 15][jr] = d.w;
            }
            if (half == 0 && t < TJ) s_x2t[t] = x2[j0 + t];
            __syncthreads();

            // compute: 8 d-quads; lane owns j-quad [4*lane .. 4*lane+3]
            #pragma unroll
            for (int dq = 0; dq < 8; ++dq) {
                float xj[4][4];   // [dd][jj]
                #pragma unroll
                for (int c = 0; c < 4; ++c) {
                    float4 q = *reinterpret_cast<const float4*>(&s_xT[dq * 4 + c][lane * 4]);
                    xj[c][0] = q.x; xj[c][1] = q.y; xj[c][2] = q.z; xj[c][3] = q.w;
                }
                float xiv[R_PW][4];
                #pragma unroll
                for (int r = 0; r < R_PW; ++r) {
                    float4 q = *reinterpret_cast<const float4*>(
                        &s_xi[my_r0 + r][half * DH + dq * 4]);
                    xiv[r][0] = q.x; xiv[r][1] = q.y; xiv[r][2] = q.z; xiv[r][3] = q.w;
                }
                #pragma unroll
                for (int r = 0; r < R_PW; ++r)
                    #pragma unroll
                    for (int dd = 0; dd < 4; ++dd)
                        #pragma unroll
                        for (int jj = 0; jj < 4; ++jj)
                            acc[r][jj] += xiv[r][dd] * xj[dd][jj];
            }
        }

        // epilogue: d2 + branchless bubble insert into sorted top-16
        float x2j[4];
        {
            float4 q = *reinterpret_cast<const float4*>(&s_x2t[lane * 4]);
            x2j[0] = q.x; x2j[1] = q.y; x2j[2] = q.z; x2j[3] = q.w;
        }
        #pragma unroll
        for (int r = 0; r < R_PW; ++r) {
            const int gi = row0 + my_r0 + r;
            #pragma unroll
            for (int jj = 0; jj < 4; ++jj) {
                const int gj = j0 + lane * 4 + jj;
                float d2 = x2i[r] + x2j[jj] - 2.f * acc[r][jj];
                float v = (gj == gi) ? INF : d2;
                #pragma unroll
                for (int k = 0; k < 16; ++k) {
                    float lo = fminf(t16[r][k], v);
                    v = fmaxf(t16[r][k], v);
                    t16[r][k] = lo;
                }
            }
        }
    }

    // per-wave merge: 16 extractions from 64 sorted lists (shfl argmin, no LDS)
    #pragma unroll
    for (int r = 0; r < R_PW; ++r) {
        float sum = 0.f;
        for (int it = 0; it < 16; ++it) {
            float v = t16[r][0];
            int id = lane;
            #pragma unroll
            for (int off = 32; off > 0; off >>= 1) {
                float ov = __shfl_xor(v, off);
                int oid = __shfl_xor(id, off);
                if (ov < v || (ov == v && oid < id)) { v = ov; id = oid; }
            }
            sum += sqrtf(fmaxf(v, 0.f));
            bool c = (lane == id);
            #pragma unroll
            for (int k = 0; k < 15; ++k) t16[r][k] = c ? t16[r][k + 1] : t16[r][k];
            t16[r][15] = c ? INF : t16[r][15];
        }
        if (lane == 0) md[row0 + my_r0 + r] = sum * (1.f / 16.f);
    }
}

__global__ __launch_bounds__(1024) void loss_kernel(
    const float* __restrict__ md, float* __restrict__ out) {
    __shared__ float s[1024];
    const int t = threadIdx.x;

    float m = -__builtin_inff();
    for (int j = t; j < N_PTS; j += 1024) m = fmaxf(m, md[j]);
    s[t] = m; __syncthreads();
    for (int off = 512; off > 0; off >>= 1) {
        if (t < off) s[t] = fmaxf(s[t], s[t + off]);
        __syncthreads();
    }
    m = s[0]; __syncthreads();

    float se = 0.f, sm = 0.f;
    for (int j = t; j < N_PTS; j += 1024) {
        float v = md[j];
        se += expf(v - m);
        sm += v;
    }
    s[t] = se; __syncthreads();
    for (int off = 512; off > 0; off >>= 1) {
        if (t < off) s[t] += s[t + off];
        __syncthreads();
    }
    float S = s[0]; __syncthreads();
    s[t] = sm; __syncthreads();
    for (int off = 512; off > 0; off >>= 1) {
        if (t < off) s[t] += s[t + off];
        __syncthreads();
    }
    float M = s[0];

    if (t == 0) {
        const float n = (float)N_PTS;
        float lse = m + logf(S);
        out[0] = -logf(n) - M / n + lse;
    }
}

extern "C" void kernel_launch(void* const* d_in, const int* in_sizes, int n_in,
                              void* d_out, int out_size, void* d_ws, size_t ws_size,
                              hipStream_t stream) {
    const float* x = (const float*)d_in[0];
    float* out = (float*)d_out;
    float* md = (float*)d_ws;                 // 8192 floats
    float* x2 = (float*)d_ws + N_PTS;         // 8192 floats

    norms_kernel<<<N_PTS / 256, 256, 0, stream>>>(x, x2);
    nn16_kernel<<<N_PTS / TM, TPB, 0, stream>>>(x, x2, md);
    loss_kernel<<<1, 1024, 0, stream>>>(md, out);
}

// Round 3
// 158.996 us; speedup vs baseline: 11.7198x; 1.6781x over previous
//
#include <hip/hip_runtime.h>
#include <hip/hip_bf16.h>
#include <math.h>

#define N_PTS 8192
#define D_FEAT 64
#define KP 128               // packed K = hi(64) || lo(64)
#define TPB 512              // 8 waves
#define ROWS_B 32            // i-rows per block
#define JT 256               // j per pass (8 waves * 32)
#define NPASS (N_PTS / JT)   // 32

typedef __attribute__((ext_vector_type(8))) short short8v;   // 8 bf16 = 4 VGPR
typedef __attribute__((ext_vector_type(16))) float f32x16;   // MFMA 32x32 acc

__device__ ushort g_X2[N_PTS * KP];   // 2 MB packed bf16 hi||lo
__device__ float  g_x2n[N_PTS];       // fp32 squared norms
__device__ float  g_md[N_PTS];        // mean NN distance per row

// ---- pack: fp32 row -> bf16 hi/lo split + fp32 norm ----
__global__ __launch_bounds__(256) void pack_kernel(const float* __restrict__ x) {
    const int row = blockIdx.x * 256 + threadIdx.x;
    const float4* xr = (const float4*)(x + (size_t)row * D_FEAT);
    ushort* outr = g_X2 + (size_t)row * KP;
    float norm = 0.f;
    #pragma unroll
    for (int it = 0; it < 8; ++it) {
        float4 a = xr[2 * it], b = xr[2 * it + 1];
        float vals[8] = {a.x, a.y, a.z, a.w, b.x, b.y, b.z, b.w};
        uint hi[8], lo[8];
        #pragma unroll
        for (int e = 0; e < 8; ++e) {
            float v = vals[e];
            norm += v * v;
            uint u = __float_as_uint(v);
            uint rh = (u + 0x7fffu + ((u >> 16) & 1u)) >> 16;   // RNE bf16
            hi[e] = rh;
            float hf = __uint_as_float(rh << 16);
            float l = v - hf;
            uint u2 = __float_as_uint(l);
            lo[e] = (u2 + 0x7fffu + ((u2 >> 16) & 1u)) >> 16;
        }
        *(uint4*)(outr + it * 8) = make_uint4(
            hi[0] | (hi[1] << 16), hi[2] | (hi[3] << 16),
            hi[4] | (hi[5] << 16), hi[6] | (hi[7] << 16));
        *(uint4*)(outr + 64 + it * 8) = make_uint4(
            lo[0] | (lo[1] << 16), lo[2] | (lo[3] << 16),
            lo[4] | (lo[5] << 16), lo[6] | (lo[7] << 16));
    }
    g_x2n[row] = norm;
}

// ---- main: fused Gram-MFMA + per-row top-16 ----
__global__ __launch_bounds__(TPB, 2) void nn_kernel() {
    __shared__ float s_mem[ROWS_B * 17 * 16];   // 8704 f: x2 cache, then merge lists
    const int t    = threadIdx.x;
    const int lane = t & 63;
    const int w    = t >> 6;       // wave 0..7
    const int il   = lane & 31;    // output col (row index i within block)
    const int h    = lane >> 5;    // half-wave (k-group / j row-group)
    const int i0   = blockIdx.x * ROWS_B;
    const float INF = __builtin_inff();

    // preload all norms into LDS (first 8192 floats of s_mem)
    {
        float4* s4 = (float4*)s_mem;
        const float4* g4 = (const float4*)g_x2n;
        #pragma unroll
        for (int q = 0; q < 4; ++q) s4[t + q * TPB] = g4[t + q * TPB];
    }

    const short8v* Xs = (const short8v*)g_X2;   // row = 16 units of 16B

    // B-frag: this block's 32 i-rows, full K=128, resident in 32 VGPRs
    short8v bfr[8];
    {
        const short8v* bp = Xs + (size_t)(i0 + il) * 16 + h;
        #pragma unroll
        for (int tt = 0; tt < 8; ++tt) bfr[tt] = bp[2 * tt];
    }
    __syncthreads();

    // per-lane sorted (ascending) top-16 of v = x2j - 2*S  (monotone in d2)
    float t16[16];
    #pragma unroll
    for (int k = 0; k < 16; ++k) t16[k] = INF;

    const short8v* abase = Xs + (size_t)(w * 32 + il) * 16 + h;

    auto loadA = [&](short8v (&dst)[8], int p) {
        #pragma unroll
        for (int tt = 0; tt < 8; ++tt) dst[tt] = abase[(size_t)p * 4096 + 2 * tt];
    };

    auto compute = [&](short8v (&af)[8], int p) {
        f32x16 acc;
        #pragma unroll
        for (int r = 0; r < 16; ++r) acc[r] = 0.f;
        #pragma unroll
        for (int tt = 0; tt < 8; ++tt)
            acc = __builtin_amdgcn_mfma_f32_32x32x16_bf16(af[tt], bfr[tt], acc, 0, 0, 0);

        const int j0w = p * JT + w * 32;
        // x2j for this lane's 16 j-candidates: j = j0w + (r&3) + 8*(r>>2) + 4h
        float4 xq0 = *(const float4*)&s_mem[j0w + 4 * h];
        float4 xq1 = *(const float4*)&s_mem[j0w + 8 + 4 * h];
        float4 xq2 = *(const float4*)&s_mem[j0w + 16 + 4 * h];
        float4 xq3 = *(const float4*)&s_mem[j0w + 24 + 4 * h];
        float x2j[16] = {xq0.x, xq0.y, xq0.z, xq0.w, xq1.x, xq1.y, xq1.z, xq1.w,
                         xq2.x, xq2.y, xq2.z, xq2.w, xq3.x, xq3.y, xq3.z, xq3.w};
        float v[16];
        #pragma unroll
        for (int r = 0; r < 16; ++r) v[r] = fmaf(-2.f, acc[r], x2j[r]);
        if (j0w == i0) {   // wave-uniform: diagonal tile, mask self-pair
            #pragma unroll
            for (int r = 0; r < 16; ++r) {
                const int jp = (r & 3) + 8 * (r >> 2) + 4 * h;
                if (jp == il) v[r] = INF;
            }
        }
        #pragma unroll
        for (int r = 0; r < 16; ++r) {
            float vv = v[r];
            if (vv < t16[15]) {           // rare after warm-up
                #pragma unroll
                for (int k = 0; k < 16; ++k) {
                    float lov = fminf(t16[k], vv);
                    vv = fmaxf(t16[k], vv);
                    t16[k] = lov;
                }
            }
        }
    };

    short8v a0[8], a1[8];
    loadA(a0, 0);
    #pragma unroll 1
    for (int pp = 0; pp < NPASS / 2; ++pp) {
        const int p1 = 2 * pp + 1;
        loadA(a1, p1);
        compute(a0, 2 * pp);
        if (pp < NPASS / 2 - 1) loadA(a0, p1 + 1);
        compute(a1, p1);
    }

    // ---- merge: 16 sorted lists per row -> global top-16 -> mean sqrt ----
    __syncthreads();   // all x2 reads done; reuse s_mem for lists[32][17(pad)][16]
    {
        float* dst = &s_mem[(il * 17 + (w * 2 + h)) * 16];
        *(float4*)(dst + 0)  = make_float4(t16[0],  t16[1],  t16[2],  t16[3]);
        *(float4*)(dst + 4)  = make_float4(t16[4],  t16[5],  t16[6],  t16[7]);
        *(float4*)(dst + 8)  = make_float4(t16[8],  t16[9],  t16[10], t16[11]);
        *(float4*)(dst + 12) = make_float4(t16[12], t16[13], t16[14], t16[15]);
    }
    __syncthreads();

    #pragma unroll 1
    for (int q = 0; q < 4; ++q) {
        const int r = 4 * w + q;
        const float* Lr = &s_mem[r * 17 * 16];
        float4 c = *(const float4*)&Lr[(lane >> 2) * 16 + (lane & 3) * 4];
        float c0 = c.x, c1 = c.y, c2 = c.z, c3 = c.w;   // sorted run of 4
        const float x2r = g_x2n[i0 + r];
        float sum = 0.f;
        #pragma unroll 1
        for (int it = 0; it < 16; ++it) {
            float m = c0; int src = lane;
            #pragma unroll
            for (int off = 32; off > 0; off >>= 1) {
                float om = __shfl_xor(m, off);
                int os = __shfl_xor(src, off);
                if (om < m || (om == m && os < src)) { m = om; src = os; }
            }
            sum += sqrtf(fmaxf(m + x2r, 0.f));
            const bool pop = (lane == src);
            c0 = pop ? c1 : c0;
            c1 = pop ? c2 : c1;
            c2 = pop ? c3 : c2;
            c3 = pop ? INF : c3;
        }
        if (lane == 0) g_md[i0 + r] = sum * (1.f / 16.f);
    }
}

// ---- scalar loss ----
__global__ __launch_bounds__(1024) void loss_kernel(float* __restrict__ out) {
    __shared__ float s[1024];
    const int t = threadIdx.x;

    float m = -__builtin_inff();
    for (int j = t; j < N_PTS; j += 1024) m = fmaxf(m, g_md[j]);
    s[t] = m; __syncthreads();
    for (int off = 512; off > 0; off >>= 1) {
        if (t < off) s[t] = fmaxf(s[t], s[t + off]);
        __syncthreads();
    }
    m = s[0]; __syncthreads();

    float se = 0.f, sm = 0.f;
    for (int j = t; j < N_PTS; j += 1024) {
        float v = g_md[j];
        se += expf(v - m);
        sm += v;
    }
    s[t] = se; __syncthreads();
    for (int off = 512; off > 0; off >>= 1) {
        if (t < off) s[t] += s[t + off];
        __syncthreads();
    }
    float S = s[0]; __syncthreads();
    s[t] = sm; __syncthreads();
    for (int off = 512; off > 0; off >>= 1) {
        if (t < off) s[t] += s[t + off];
        __syncthreads();
    }
    float M = s[0];

    if (t == 0) {
        const float n = (float)N_PTS;
        out[0] = -logf(n) - M / n + (m + logf(S));
    }
}

extern "C" void kernel_launch(void* const* d_in, const int* in_sizes, int n_in,
                              void* d_out, int out_size, void* d_ws, size_t ws_size,
                              hipStream_t stream) {
    const float* x = (const float*)d_in[0];
    float* out = (float*)d_out;

    pack_kernel<<<N_PTS / 256, 256, 0, stream>>>(x);
    nn_kernel<<<N_PTS / ROWS_B, TPB, 0, stream>>>();
    loss_kernel<<<1, 1024, 0, stream>>>(out);
}